// Round 3
// baseline (140.395 us; speedup 1.0000x reference)
//
#include <hip/hip_runtime.h>
#include <math.h>

#define BB 16
#define NBB 512
#define BSS 128
#define KK 32
#define NBLK (BB*NBB)        // 8192 query blocks
#define STATS_GRID 1024      // 1,048,576 elems / (256 thr * 4 elem)

// W (float) layout (all qb-indexed arrays packed for kernel-2 access pattern):
//   [0     ..16384)   VC   float2 per qblock: {Svp (sum vld*p), Cv (count vld)}
//   [16384 ..49152)   SU   float4 per qblock: {Sup, Sup2, Cu, 0}
//   [49152 ..65536)   BC   float2 per qblock: {bceSum, bceCnt}
//   [65536 ..65600)   P4   per-batch accumulators: [16]x{loss, nunc, bs, bc}
//   [65600 ..65617)   tickets (int): [16] per-batch + [1] global

#define VC_OFF 0
#define SU_OFF 16384
#define BC_OFF 49152
#define P_OFF  65536
#define TICKET_OFF 65600

// Kernel 1: per-query-block stats, vectorized. 1024 blocks x 256 threads;
// each thread handles 4 contiguous elements (float4), so each 32-lane group
// covers exactly one 128-element query block. Mask encoding (1-byte bool vs
// 4-byte word) detected per block by sampling 1024 bytes at offset%4==1 in
// the first 4KB of sup (nonzero there only possible for byte-packed bools;
// ~10% true density => miss prob 0.9^1024 ~ 1e-47).
__global__ __launch_bounds__(256) void stats_kernel(
    const float* __restrict__ logits, const float* __restrict__ targets,
    const unsigned char* __restrict__ sup_b, const unsigned char* __restrict__ ign_b,
    float* __restrict__ W)
{
    const int t = threadIdx.x;
    __shared__ int s_mode;
    if (t == 0) s_mode = 0;
    __syncthreads();
    int local = 0;
    #pragma unroll
    for (int r = 0; r < 4; ++r) {
        if (sup_b[4 * (t + 256 * r) + 1] != 0) local = 1;
    }
    if (local) atomicOr(&s_mode, 1);
    __syncthreads();
    const bool byteMode = (s_mode != 0);

    const int gid = blockIdx.x * 256 + t;          // float4 index
    const float4 x4 = ((const float4*)logits)[gid];
    const float4 t4 = ((const float4*)targets)[gid];
    bool s[4], g[4];
    if (byteMode) {
        const unsigned int sm = ((const unsigned int*)sup_b)[gid];
        const unsigned int gm = ((const unsigned int*)ign_b)[gid];
        #pragma unroll
        for (int j = 0; j < 4; ++j) {
            s[j] = ((sm >> (8 * j)) & 0xffu) != 0;
            g[j] = ((gm >> (8 * j)) & 0xffu) != 0;
        }
    } else {
        const int4 sm = ((const int4*)sup_b)[gid];
        const int4 gm = ((const int4*)ign_b)[gid];
        s[0] = sm.x != 0; s[1] = sm.y != 0; s[2] = sm.z != 0; s[3] = sm.w != 0;
        g[0] = gm.x != 0; g[1] = gm.y != 0; g[2] = gm.z != 0; g[3] = gm.w != 0;
    }
    const float xs[4] = {x4.x, x4.y, x4.z, x4.w};
    const float ts[4] = {t4.x, t4.y, t4.z, t4.w};

    float svp = 0.f, cv = 0.f, su = 0.f, su2 = 0.f, cu = 0.f, bs = 0.f, bc = 0.f;
    #pragma unroll
    for (int j = 0; j < 4; ++j) {
        const float x = xs[j];
        const float p = 1.0f / (1.0f + expf(-x));
        if (s[j]) {
            bs += fmaxf(x, 0.0f) - x * ts[j] + log1pf(expf(-fabsf(x)));
            bc += 1.0f;
        }
        if (!g[j]) {
            svp += p; cv += 1.0f;
            if (!s[j]) { su += p; su2 += p * p; cu += 1.0f; }
        }
    }
    // width-32 group reduction: each 32-lane group = one query block
    #pragma unroll
    for (int off = 16; off > 0; off >>= 1) {
        svp += __shfl_down(svp, off, 32);
        cv  += __shfl_down(cv,  off, 32);
        su  += __shfl_down(su,  off, 32);
        su2 += __shfl_down(su2, off, 32);
        cu  += __shfl_down(cu,  off, 32);
        bs  += __shfl_down(bs,  off, 32);
        bc  += __shfl_down(bc,  off, 32);
    }
    if ((t & 31) == 0) {
        const int qb = blockIdx.x * 8 + (t >> 5);  // global query-block id
        ((float2*)(W + VC_OFF))[qb] = make_float2(svp, cv);
        ((float4*)(W + SU_OFF))[qb] = make_float4(su, su2, cu, 0.0f);
        ((float2*)(W + BC_OFF))[qb] = make_float2(bs, bc);
    }
    // zero the accumulators + tickets for kernel 2 (stream-ordered after us)
    if (blockIdx.x == 0 && t < 64) W[P_OFF + t] = 0.0f;
    if (blockIdx.x == 0 && t < 17) ((int*)(W + TICKET_OFF))[t] = 0;
}

// Kernel 2: neighbor aggregation, fully slot-parallel. 1024 blocks x 256
// threads = 262144 threads = one thread per (qblock, k-slot). Each 32-lane
// group handles ONE query block: coalesced kv_idx read, one packed {Svp,Cv}
// float2 gather per lane, width-32 butterfly reduce — no serial k loop.
// Per-batch accumulators (16x4 floats) + hierarchical tickets (64-way per
// batch, then 16-way global) keep same-address atomic contention low.
__global__ __launch_bounds__(256) void graph_kernel(
    const int* __restrict__ kv_idx, const int* __restrict__ kv_nb,
    float* __restrict__ W, float* __restrict__ out)
{
    const int t    = threadIdx.x;
    const int grp  = t >> 5;                 // 0..7
    const int slot = t & 31;                 // k-slot
    const int gb   = blockIdx.x * 8 + grp;   // global qblock id (one per group)
    const int b    = blockIdx.x >> 6;        // 64 blocks per batch (512/8)

    const float2* __restrict__ VC  = (const float2*)(W + VC_OFF);
    const float4* __restrict__ SU  = (const float4*)(W + SU_OFF);
    const float2* __restrict__ BCp = (const float2*)(W + BC_OFF);
    float* P      = W + P_OFF;               // [16] x {loss, nunc, bs, bc}
    int* btick    = (int*)(W + TICKET_OFF);  // [16] per-batch tickets
    int* gtick    = btick + 16;              // global ticket

    const int knb = kv_nb[gb];
    float psum = 0.f, cnt = 0.f;
    if (slot < knb) {
        const int j = kv_idx[(size_t)gb * KK + slot]; // coalesced per group
        const float2 vc = VC[(b << 9) + j];           // single 8B gather
        psum = vc.x; cnt = vc.y;
    }
    #pragma unroll
    for (int m = 16; m > 0; m >>= 1) {
        psum += __shfl_xor(psum, m, 32);
        cnt  += __shfl_xor(cnt,  m, 32);
    }

    float loss = 0.f, nunc = 0.f, bs = 0.f, bc = 0.f;
    if (slot == 0) {
        const float4 su  = SU[gb];
        const float2 bcv = BCp[gb];
        bs = bcv.x; bc = bcv.y;
        if (su.z > 0.0f && knb > 0 && cnt > 0.0f) {
            const float mm = psum / fmaxf(cnt, 1.0f);
            loss = su.y - 2.0f * mm * su.x + mm * mm * su.z;
            nunc = su.z;
        }
    }

    __shared__ float s[8][4];
    if (slot == 0) {
        s[grp][0] = loss; s[grp][1] = nunc; s[grp][2] = bs; s[grp][3] = bc;
    }
    __syncthreads();
    if (t == 0) {
        float l = 0.f, n = 0.f, b2s = 0.f, b2c = 0.f;
        #pragma unroll
        for (int g = 0; g < 8; ++g) {
            l += s[g][0]; n += s[g][1]; b2s += s[g][2]; b2c += s[g][3];
        }
        atomicAdd(&P[b * 4 + 0], l);
        atomicAdd(&P[b * 4 + 1], n);
        atomicAdd(&P[b * 4 + 2], b2s);
        atomicAdd(&P[b * 4 + 3], b2c);
        __threadfence();
        const int brank = atomicAdd(&btick[b], 1);
        if (brank == 63) {                       // last block of this batch
            __threadfence();
            const int grank = atomicAdd(gtick, 1);
            if (grank == 15) {                   // last batch: finalize
                __threadfence();
                float gsum = 0.f, nval = 0.f, tbs = 0.f, tbc = 0.f;
                for (int b2 = 0; b2 < BB; ++b2) {
                    const float lv = atomicAdd(&P[b2 * 4 + 0], 0.0f);  // coherent read
                    const float nv = atomicAdd(&P[b2 * 4 + 1], 0.0f);
                    tbs += atomicAdd(&P[b2 * 4 + 2], 0.0f);
                    tbc += atomicAdd(&P[b2 * 4 + 3], 0.0f);
                    if (nv > 0.0f) { gsum += lv / fmaxf(nv, 1.0f); nval += 1.0f; }
                }
                out[0] = tbs / fmaxf(tbc, 1.0f) + 0.3f * (gsum / fmaxf(nval, 1.0f));
            }
        }
    }
}

extern "C" void kernel_launch(void* const* d_in, const int* in_sizes, int n_in,
                              void* d_out, int out_size, void* d_ws, size_t ws_size,
                              hipStream_t stream) {
    (void)in_sizes; (void)n_in; (void)out_size; (void)ws_size;
    const float* logits  = (const float*)d_in[0];
    const float* targets = (const float*)d_in[1];
    const unsigned char* supm = (const unsigned char*)d_in[2];
    const unsigned char* ignm = (const unsigned char*)d_in[3];
    const int* kv_idx = (const int*)d_in[4];
    const int* kv_nb  = (const int*)d_in[5];
    float* W   = (float*)d_ws;
    float* out = (float*)d_out;

    hipLaunchKernelGGL(stats_kernel, dim3(STATS_GRID), dim3(256), 0, stream,
                       logits, targets, supm, ignm, W);
    hipLaunchKernelGGL(graph_kernel, dim3(1024), dim3(256), 0, stream,
                       kv_idx, kv_nb, W, out);
}

// Round 4
// 86.347 us; speedup vs baseline: 1.6259x; 1.6259x over previous
//
#include <hip/hip_runtime.h>
#include <math.h>

#define BB 16
#define NBB 512
#define BSS 128
#define KK 32
#define NBLK (BB*NBB)        // 8192 query blocks
#define STATS_GRID 1024      // 1,048,576 elems / (256 thr * 4 elem)

// W (float) layout (all qb-indexed arrays packed for kernel-2 access pattern):
//   [0     ..16384)   VC   float2 per qblock: {Svp (sum vld*p), Cv (count vld)}
//   [16384 ..49152)   SU   float4 per qblock: {Sup, Sup2, Cu, 0}
//   [49152 ..65536)   BC   float2 per qblock: {bceSum, bceCnt}
//   [65536 ..69632)   GP   float4 per graph block: {loss, nunc, bs, bc}
// No atomics, no tickets, no fences anywhere: kernel boundaries on the
// stream provide all ordering/visibility (round-3 lesson: 1024 blocks of
// device-scope atomicAdd+threadfence serialized at ~61 ns/block = 63 us).

#define VC_OFF 0
#define SU_OFF 16384
#define BC_OFF 49152
#define GP_OFF 65536

// Kernel 1: per-query-block stats, vectorized. 1024 blocks x 256 threads;
// each thread handles 4 contiguous elements (float4), so each 32-lane group
// covers exactly one 128-element query block. Mask encoding (1-byte bool vs
// 4-byte word) detected per block by sampling 1024 bytes at offset%4==1 in
// the first 4KB of sup (nonzero there only possible for byte-packed bools;
// ~10% true density => miss prob 0.9^1024 ~ 1e-47).
__global__ __launch_bounds__(256) void stats_kernel(
    const float* __restrict__ logits, const float* __restrict__ targets,
    const unsigned char* __restrict__ sup_b, const unsigned char* __restrict__ ign_b,
    float* __restrict__ W)
{
    const int t = threadIdx.x;
    __shared__ int s_mode;
    if (t == 0) s_mode = 0;
    __syncthreads();
    int local = 0;
    #pragma unroll
    for (int r = 0; r < 4; ++r) {
        if (sup_b[4 * (t + 256 * r) + 1] != 0) local = 1;
    }
    if (local) atomicOr(&s_mode, 1);
    __syncthreads();
    const bool byteMode = (s_mode != 0);

    const int gid = blockIdx.x * 256 + t;          // float4 index
    const float4 x4 = ((const float4*)logits)[gid];
    const float4 t4 = ((const float4*)targets)[gid];
    bool s[4], g[4];
    if (byteMode) {
        const unsigned int sm = ((const unsigned int*)sup_b)[gid];
        const unsigned int gm = ((const unsigned int*)ign_b)[gid];
        #pragma unroll
        for (int j = 0; j < 4; ++j) {
            s[j] = ((sm >> (8 * j)) & 0xffu) != 0;
            g[j] = ((gm >> (8 * j)) & 0xffu) != 0;
        }
    } else {
        const int4 sm = ((const int4*)sup_b)[gid];
        const int4 gm = ((const int4*)ign_b)[gid];
        s[0] = sm.x != 0; s[1] = sm.y != 0; s[2] = sm.z != 0; s[3] = sm.w != 0;
        g[0] = gm.x != 0; g[1] = gm.y != 0; g[2] = gm.z != 0; g[3] = gm.w != 0;
    }
    const float xs[4] = {x4.x, x4.y, x4.z, x4.w};
    const float ts[4] = {t4.x, t4.y, t4.z, t4.w};

    float svp = 0.f, cv = 0.f, su = 0.f, su2 = 0.f, cu = 0.f, bs = 0.f, bc = 0.f;
    #pragma unroll
    for (int j = 0; j < 4; ++j) {
        const float x = xs[j];
        const float p = 1.0f / (1.0f + expf(-x));
        if (s[j]) {
            bs += fmaxf(x, 0.0f) - x * ts[j] + log1pf(expf(-fabsf(x)));
            bc += 1.0f;
        }
        if (!g[j]) {
            svp += p; cv += 1.0f;
            if (!s[j]) { su += p; su2 += p * p; cu += 1.0f; }
        }
    }
    // width-32 group reduction: each 32-lane group = one query block
    #pragma unroll
    for (int off = 16; off > 0; off >>= 1) {
        svp += __shfl_down(svp, off, 32);
        cv  += __shfl_down(cv,  off, 32);
        su  += __shfl_down(su,  off, 32);
        su2 += __shfl_down(su2, off, 32);
        cu  += __shfl_down(cu,  off, 32);
        bs  += __shfl_down(bs,  off, 32);
        bc  += __shfl_down(bc,  off, 32);
    }
    if ((t & 31) == 0) {
        const int qb = blockIdx.x * 8 + (t >> 5);  // global query-block id
        ((float2*)(W + VC_OFF))[qb] = make_float2(svp, cv);
        ((float4*)(W + SU_OFF))[qb] = make_float4(su, su2, cu, 0.0f);
        ((float2*)(W + BC_OFF))[qb] = make_float2(bs, bc);
    }
}

// Kernel 2: neighbor aggregation, fully slot-parallel. 1024 blocks x 256
// threads = one thread per (qblock, k-slot). Each 32-lane group handles ONE
// query block: coalesced kv_idx read, one packed {Svp,Cv} float2 gather per
// lane, width-32 butterfly reduce. Block writes ONE plain float4 partial —
// no atomics/fences (they serialized at ~61 ns/block in round 3).
__global__ __launch_bounds__(256) void graph_kernel(
    const int* __restrict__ kv_idx, const int* __restrict__ kv_nb,
    float* __restrict__ W)
{
    const int t    = threadIdx.x;
    const int grp  = t >> 5;                 // 0..7
    const int slot = t & 31;                 // k-slot
    const int gb   = blockIdx.x * 8 + grp;   // global qblock id (one per group)
    const int b    = blockIdx.x >> 6;        // 64 blocks per batch (512/8)

    const float2* __restrict__ VC  = (const float2*)(W + VC_OFF);
    const float4* __restrict__ SU  = (const float4*)(W + SU_OFF);
    const float2* __restrict__ BCp = (const float2*)(W + BC_OFF);

    const int knb = kv_nb[gb];
    float psum = 0.f, cnt = 0.f;
    if (slot < knb) {
        const int j = kv_idx[(size_t)gb * KK + slot]; // coalesced per group
        const float2 vc = VC[(b << 9) + j];           // single 8B gather
        psum = vc.x; cnt = vc.y;
    }
    #pragma unroll
    for (int m = 16; m > 0; m >>= 1) {
        psum += __shfl_xor(psum, m, 32);
        cnt  += __shfl_xor(cnt,  m, 32);
    }

    float loss = 0.f, nunc = 0.f, bs = 0.f, bc = 0.f;
    if (slot == 0) {
        const float4 su  = SU[gb];
        const float2 bcv = BCp[gb];
        bs = bcv.x; bc = bcv.y;
        if (su.z > 0.0f && knb > 0 && cnt > 0.0f) {
            const float mm = psum / fmaxf(cnt, 1.0f);
            loss = su.y - 2.0f * mm * su.x + mm * mm * su.z;
            nunc = su.z;
        }
    }

    __shared__ float s[8][4];
    if (slot == 0) {
        s[grp][0] = loss; s[grp][1] = nunc; s[grp][2] = bs; s[grp][3] = bc;
    }
    __syncthreads();
    if (t == 0) {
        float l = 0.f, n = 0.f, b2s = 0.f, b2c = 0.f;
        #pragma unroll
        for (int g = 0; g < 8; ++g) {
            l += s[g][0]; n += s[g][1]; b2s += s[g][2]; b2c += s[g][3];
        }
        ((float4*)(W + GP_OFF))[blockIdx.x] = make_float4(l, n, b2s, b2c);
    }
}

// Kernel 3: finalize. 1 block x 256 threads reads the 1024 float4 partials
// (16 KB, L2-resident). Batch b owns partials [b*64, b*64+64); 16 threads
// per batch, 4 coalesced float4 loads each, width-16 shuffle reduce, then
// thread 0 combines the 16 batch results.
__global__ __launch_bounds__(256) void finalize_kernel(
    const float* __restrict__ W, float* __restrict__ out)
{
    const int t = threadIdx.x;
    const int b = t >> 4;                    // batch 0..15
    const int w = t & 15;                    // within-batch lane 0..15
    const float4* __restrict__ GP = (const float4*)(W + GP_OFF);

    float l = 0.f, n = 0.f, bs = 0.f, bc = 0.f;
    #pragma unroll
    for (int r = 0; r < 4; ++r) {
        const float4 v = GP[b * 64 + w + r * 16];
        l += v.x; n += v.y; bs += v.z; bc += v.w;
    }
    #pragma unroll
    for (int m = 8; m > 0; m >>= 1) {
        l  += __shfl_down(l,  m, 16);
        n  += __shfl_down(n,  m, 16);
        bs += __shfl_down(bs, m, 16);
        bc += __shfl_down(bc, m, 16);
    }
    __shared__ float sb[16][4];
    if (w == 0) { sb[b][0] = l; sb[b][1] = n; sb[b][2] = bs; sb[b][3] = bc; }
    __syncthreads();
    if (t == 0) {
        float gsum = 0.f, nval = 0.f, tbs = 0.f, tbc = 0.f;
        #pragma unroll
        for (int b2 = 0; b2 < BB; ++b2) {
            const float lv = sb[b2][0];
            const float nv = sb[b2][1];
            tbs += sb[b2][2];
            tbc += sb[b2][3];
            if (nv > 0.0f) { gsum += lv / fmaxf(nv, 1.0f); nval += 1.0f; }
        }
        out[0] = tbs / fmaxf(tbc, 1.0f) + 0.3f * (gsum / fmaxf(nval, 1.0f));
    }
}

extern "C" void kernel_launch(void* const* d_in, const int* in_sizes, int n_in,
                              void* d_out, int out_size, void* d_ws, size_t ws_size,
                              hipStream_t stream) {
    (void)in_sizes; (void)n_in; (void)out_size; (void)ws_size;
    const float* logits  = (const float*)d_in[0];
    const float* targets = (const float*)d_in[1];
    const unsigned char* supm = (const unsigned char*)d_in[2];
    const unsigned char* ignm = (const unsigned char*)d_in[3];
    const int* kv_idx = (const int*)d_in[4];
    const int* kv_nb  = (const int*)d_in[5];
    float* W   = (float*)d_ws;
    float* out = (float*)d_out;

    hipLaunchKernelGGL(stats_kernel, dim3(STATS_GRID), dim3(256), 0, stream,
                       logits, targets, supm, ignm, W);
    hipLaunchKernelGGL(graph_kernel, dim3(1024), dim3(256), 0, stream,
                       kv_idx, kv_nb, W);
    hipLaunchKernelGGL(finalize_kernel, dim3(1), dim3(256), 0, stream,
                       W, out);
}